// Round 6
// baseline (331.994 us; speedup 1.0000x reference)
//
#include <hip/hip_runtime.h>

#define N_NODES 100000
#define N_EDGES 1600000
#define D 128
#define NBUCK 782           // ceil(N_NODES / 128)
#define BSTRIDE 2560        // fixed slots per bucket (avg 2046, +5 sigma safe)

typedef __attribute__((ext_vector_type(8))) short short8v;
typedef __attribute__((ext_vector_type(4))) float f32x4;

__device__ __forceinline__ unsigned short f2bf(float f) {
    unsigned int u = __float_as_uint(f);
    unsigned int r = (u + 0x7fffu + ((u >> 16) & 1u)) >> 16;
    return (unsigned short)r;
}
__device__ __forceinline__ float bf2f(unsigned int lo16) {
    return __uint_as_float(lo16 << 16);
}
__device__ __forceinline__ short8v zero8() {
    short8v z = {0, 0, 0, 0, 0, 0, 0, 0};
    return z;
}

// ---------------- prep: pack weights bf16, zero bucket cursors ----------------
__global__ void k_prep(const float* __restrict__ W1l, const float* __restrict__ W1r,
                       const float* __restrict__ W2l, const float* __restrict__ W2r,
                       unsigned short* __restrict__ wc1, unsigned short* __restrict__ wc2,
                       int* __restrict__ gcnt) {
    int idx = blockIdx.x * 256 + threadIdx.x;
    if (idx < 16384)       wc1[idx] = f2bf(W1l[idx]);
    else if (idx < 32768)  wc1[idx] = f2bf(W1r[idx - 16384]);
    else if (idx < 49152)  wc2[idx - 32768] = f2bf(W2l[idx - 32768]);
    else if (idx < 65536)  wc2[idx - 32768] = f2bf(W2r[idx - 49152]);
    else if (idx - 65536 < NBUCK) gcnt[idx - 65536] = 0;
}

// ---------------- scatter edges into fixed-stride buckets (by dst>>7) ----------------
__global__ __launch_bounds__(256) void k_bscatter(const int* __restrict__ src,
                                                  const int* __restrict__ dst,
                                                  int* __restrict__ gcnt,
                                                  unsigned int* __restrict__ ebuf) {
    __shared__ int cnt[NBUCK];
    __shared__ int base[NBUCK];
    const int t = threadIdx.x;
    const int e0 = blockIdx.x * 4096;
    for (int i = t; i < NBUCK; i += 256) cnt[i] = 0;
    __syncthreads();
#pragma unroll
    for (int u = 0; u < 16; ++u) {
        int e = e0 + u * 256 + t;
        if (e < N_EDGES) atomicAdd(&cnt[dst[e] >> 7], 1);
    }
    __syncthreads();
    for (int i = t; i < NBUCK; i += 256) {
        int c = cnt[i];
        base[i] = c ? atomicAdd(&gcnt[i], c) : 0;
        cnt[i] = 0;
    }
    __syncthreads();
#pragma unroll
    for (int u = 0; u < 16; ++u) {
        int e = e0 + u * 256 + t;
        if (e < N_EDGES) {
            int d = dst[e];
            int b = d >> 7;
            int pos = b * BSTRIDE + base[b] + atomicAdd(&cnt[b], 1);
            __builtin_nontemporal_store(
                ((unsigned int)(d & 127) << 17) | (unsigned int)src[e], &ebuf[pos]);
        }
    }
}

// ---------------- per-bucket counting sort by local dst ----------------
__global__ __launch_bounds__(256) void k_bsort(const unsigned int* __restrict__ ebuf,
                                               const int* __restrict__ gcnt,
                                               int* __restrict__ row_start,
                                               int* __restrict__ ssrc) {
    __shared__ int h[128];
    __shared__ int sc[128];
    const int b = blockIdx.x;
    const int t = threadIdx.x;
    const int eb = b * BSTRIDE;
    const int n = gcnt[b];
    if (t < 128) h[t] = 0;
    __syncthreads();
    for (int e = t; e < n; e += 256)
        atomicAdd(&h[ebuf[eb + e] >> 17], 1);
    __syncthreads();
    if (t < 128) sc[t] = h[t];
    __syncthreads();
    for (int o = 1; o < 128; o <<= 1) {
        int add = 0;
        if (t < 128 && t >= o) add = sc[t - o];
        __syncthreads();
        if (t < 128) sc[t] += add;
        __syncthreads();
    }
    if (t < 128) {
        int excl = sc[t] - h[t];
        row_start[b * 129 + t] = eb + excl;
        h[t] = excl;            // becomes cursor
    }
    if (t == 0) row_start[b * 129 + 128] = eb + n;
    __syncthreads();
    for (int e = t; e < n; e += 256) {
        unsigned int pk = ebuf[eb + e];
        int dl = pk >> 17;
        int pos = eb + atomicAdd(&h[dl], 1);
        __builtin_nontemporal_store((int)(pk & 0x1ffffu), &ssrc[pos]);
    }
}

// ---------------- fused bf16 MFMA GEMM: [N x 128] @ [128 x 256] ----------------
template <bool A_F32, bool OUT_F32>
__global__ __launch_bounds__(256) void k_gemm_mfma(
    const void* __restrict__ Ain,
    const unsigned short* __restrict__ Bt,
    const float* __restrict__ bias,
    unsigned short* __restrict__ Tout,
    void* __restrict__ Hout)
{
    const int wid = threadIdx.x >> 6;
    const int lane = threadIdx.x & 63;
    const int l15 = lane & 15, lg = lane >> 4;
    const int col_base = wid * 64;

    short8v bfrag[4][4];
#pragma unroll
    for (int cg = 0; cg < 4; ++cg)
#pragma unroll
        for (int ks = 0; ks < 4; ++ks)
            bfrag[cg][ks] = *(const short8v*)&Bt[(size_t)(col_base + cg * 16 + l15) * 128
                                                 + ks * 32 + lg * 8];
    float bv[4];
#pragma unroll
    for (int cg = 0; cg < 4; ++cg)
        bv[cg] = (wid >= 2) ? bias[(wid - 2) * 64 + cg * 16 + l15] : 0.0f;

    const int ntiles = (N_NODES + 63) / 64;
    for (int tile = blockIdx.x; tile < ntiles; tile += gridDim.x) {
        const int row0 = tile * 64;
        f32x4 acc[4][4];
#pragma unroll
        for (int rg = 0; rg < 4; ++rg)
#pragma unroll
            for (int cg = 0; cg < 4; ++cg)
                acc[rg][cg] = (f32x4){0.f, 0.f, 0.f, 0.f};

#pragma unroll
        for (int rg = 0; rg < 4; ++rg) {
            const int arow = row0 + rg * 16 + l15;
            short8v afrag[4];
            if (arow < N_NODES) {
                if (A_F32) {
                    const float* Af = (const float*)Ain;
#pragma unroll
                    for (int ks = 0; ks < 4; ++ks) {
                        float4 p0 = *(const float4*)&Af[(size_t)arow * 128 + ks * 32 + lg * 8];
                        float4 p1 = *(const float4*)&Af[(size_t)arow * 128 + ks * 32 + lg * 8 + 4];
                        short8v f;
                        f[0] = (short)f2bf(p0.x); f[1] = (short)f2bf(p0.y);
                        f[2] = (short)f2bf(p0.z); f[3] = (short)f2bf(p0.w);
                        f[4] = (short)f2bf(p1.x); f[5] = (short)f2bf(p1.y);
                        f[6] = (short)f2bf(p1.z); f[7] = (short)f2bf(p1.w);
                        afrag[ks] = f;
                    }
                } else {
                    const unsigned short* Ab = (const unsigned short*)Ain;
#pragma unroll
                    for (int ks = 0; ks < 4; ++ks)
                        afrag[ks] = *(const short8v*)&Ab[(size_t)arow * 128 + ks * 32 + lg * 8];
                }
            } else {
#pragma unroll
                for (int ks = 0; ks < 4; ++ks) afrag[ks] = zero8();
            }
#pragma unroll
            for (int cg = 0; cg < 4; ++cg)
#pragma unroll
                for (int ks = 0; ks < 4; ++ks)
                    acc[rg][cg] = __builtin_amdgcn_mfma_f32_16x16x32_bf16(
                        afrag[ks], bfrag[cg][ks], acc[rg][cg], 0, 0, 0);
        }

        if (wid < 2) {
#pragma unroll
            for (int rg = 0; rg < 4; ++rg) {
                const int rbase = row0 + rg * 16 + lg * 4;
#pragma unroll
                for (int cg = 0; cg < 4; ++cg) {
                    const int col = col_base + cg * 16 + l15;
#pragma unroll
                    for (int i = 0; i < 4; ++i) {
                        int row = rbase + i;
                        if (row < N_NODES)
                            __builtin_nontemporal_store(f2bf(acc[rg][cg][i]),
                                &Tout[(size_t)row * 128 + col]);
                    }
                }
            }
        } else {
#pragma unroll
            for (int rg = 0; rg < 4; ++rg) {
                const int rbase = row0 + rg * 16 + lg * 4;
#pragma unroll
                for (int cg = 0; cg < 4; ++cg) {
                    const int col = (wid - 2) * 64 + cg * 16 + l15;
#pragma unroll
                    for (int i = 0; i < 4; ++i) {
                        int row = rbase + i;
                        if (row < N_NODES) {
                            float v = acc[rg][cg][i] + bv[cg];
                            if (OUT_F32)
                                __builtin_nontemporal_store(v,
                                    &((float*)Hout)[(size_t)row * 128 + col]);
                            else
                                __builtin_nontemporal_store(f2bf(v),
                                    &((unsigned short*)Hout)[(size_t)row * 128 + col]);
                        }
                    }
                }
            }
        }
    }
}

// ---------------- pull aggregation: wave per node, register acc, 8-deep MLP ----------------
// nt on ssrc/io (stream-once) so L2 keeps t_mat lines for the random gather.
template <bool RELU, bool IOF32>
__global__ __launch_bounds__(256) void k_agg(
    const unsigned short* __restrict__ t_mat,   // [N][128] bf16
    const int* __restrict__ ssrc,               // srcs sorted by dst (bucket-local CSR)
    const int* __restrict__ row_start,          // 129 per bucket
    void* __restrict__ io)                      // bf16 or f32, in-place update
{
    int w = (blockIdx.x * blockDim.x + threadIdx.x) >> 6;
    int lane = threadIdx.x & 63;
    if (w >= N_NODES) return;
    const int b = w >> 7, dl = w & 127;
    const int rs = row_start[b * 129 + dl];
    const int re = row_start[b * 129 + dl + 1];
    const int d = re - rs;

    // issue io load early; latency hides under the gather loop
    float cx, cy;
    if (IOF32) {
        const float* o = (const float*)io + (size_t)w * 128 + lane * 2;
        cx = __builtin_nontemporal_load(o);
        cy = __builtin_nontemporal_load(o + 1);
    } else {
        const unsigned int* o = (const unsigned int*)io + (size_t)w * 64 + lane;
        unsigned int cur = __builtin_nontemporal_load(o);
        cx = bf2f(cur & 0xffffu);
        cy = __uint_as_float(cur & 0xffff0000u);
    }

    const unsigned int* tlane = (const unsigned int*)t_mat + lane;   // +j*64 per row
    float ax = 0.f, ay = 0.f;
    for (int q0 = rs; q0 < re; q0 += 64) {
        int nb = 0;
        if (q0 + lane < re) nb = __builtin_nontemporal_load(&ssrc[q0 + lane]);
        const int m = min(64, re - q0);
        int q = 0;
        for (; q + 8 <= m; q += 8) {
            unsigned int v0 = tlane[(size_t)__shfl(nb, q) * 64];
            unsigned int v1 = tlane[(size_t)__shfl(nb, q + 1) * 64];
            unsigned int v2 = tlane[(size_t)__shfl(nb, q + 2) * 64];
            unsigned int v3 = tlane[(size_t)__shfl(nb, q + 3) * 64];
            unsigned int v4 = tlane[(size_t)__shfl(nb, q + 4) * 64];
            unsigned int v5 = tlane[(size_t)__shfl(nb, q + 5) * 64];
            unsigned int v6 = tlane[(size_t)__shfl(nb, q + 6) * 64];
            unsigned int v7 = tlane[(size_t)__shfl(nb, q + 7) * 64];
            ax += bf2f(v0 & 0xffffu) + bf2f(v1 & 0xffffu)
                + bf2f(v2 & 0xffffu) + bf2f(v3 & 0xffffu)
                + bf2f(v4 & 0xffffu) + bf2f(v5 & 0xffffu)
                + bf2f(v6 & 0xffffu) + bf2f(v7 & 0xffffu);
            ay += __uint_as_float(v0 & 0xffff0000u) + __uint_as_float(v1 & 0xffff0000u)
                + __uint_as_float(v2 & 0xffff0000u) + __uint_as_float(v3 & 0xffff0000u)
                + __uint_as_float(v4 & 0xffff0000u) + __uint_as_float(v5 & 0xffff0000u)
                + __uint_as_float(v6 & 0xffff0000u) + __uint_as_float(v7 & 0xffff0000u);
        }
        for (; q < m; ++q) {
            unsigned int v = tlane[(size_t)__shfl(nb, q) * 64];
            ax += bf2f(v & 0xffffu);
            ay += __uint_as_float(v & 0xffff0000u);
        }
    }
    const float inv = 1.0f / (float)max(d, 1);
    float rx = cx + inv * ax;
    float ry = cy + inv * ay;
    if (RELU) { rx = fmaxf(rx, 0.f); ry = fmaxf(ry, 0.f); }
    if (IOF32) {
        float* o = (float*)io + (size_t)w * 128 + lane * 2;
        __builtin_nontemporal_store(rx, o);
        __builtin_nontemporal_store(ry, o + 1);
    } else {
        unsigned int* o = (unsigned int*)io + (size_t)w * 64 + lane;
        __builtin_nontemporal_store(
            (unsigned int)f2bf(rx) | ((unsigned int)f2bf(ry) << 16), o);
    }
}

// ---------------- launch ----------------

extern "C" void kernel_launch(void* const* d_in, const int* in_sizes, int n_in,
                              void* d_out, int out_size, void* d_ws, size_t ws_size,
                              hipStream_t stream) {
    const float* x   = (const float*)d_in[0];
    const int*   ei  = (const int*)d_in[1];
    const float* W1l = (const float*)d_in[2];
    const float* W1r = (const float*)d_in[3];
    const float* b1  = (const float*)d_in[4];
    const float* W2l = (const float*)d_in[5];
    const float* W2r = (const float*)d_in[6];
    const float* b2  = (const float*)d_in[7];
    float* out = (float*)d_out;

    const int* src = ei;
    const int* dst = ei + N_EDGES;

    char* p = (char*)d_ws;
    auto alloc = [&](size_t bytes) {
        char* r = p;
        p += (bytes + 255) & ~(size_t)255;
        return r;
    };
    unsigned short* tb = (unsigned short*)alloc((size_t)N_NODES * D * 2);   // 25.6MB
    unsigned short* hx = (unsigned short*)alloc((size_t)N_NODES * D * 2);   // 25.6MB
    unsigned int*   ebuf = (unsigned int*)alloc((size_t)NBUCK * BSTRIDE * 4); // 8MB
    int*   ssrc      = (int*)alloc((size_t)NBUCK * BSTRIDE * 4);              // 8MB
    int*   gcnt      = (int*)alloc(NBUCK * sizeof(int));
    int*   row_start = (int*)alloc((size_t)NBUCK * 129 * sizeof(int));
    unsigned short* wc1 = (unsigned short*)alloc(256 * 128 * 2);
    unsigned short* wc2 = (unsigned short*)alloc(256 * 128 * 2);

    // prep (weights + cursor zero) -> scatter -> per-bucket sort
    k_prep<<<(65536 + NBUCK + 255) / 256, 256, 0, stream>>>(W1l, W1r, W2l, W2r, wc1, wc2, gcnt);
    k_bscatter<<<(N_EDGES + 4095) / 4096, 256, 0, stream>>>(src, dst, gcnt, ebuf);
    k_bsort<<<NBUCK, 256, 0, stream>>>(ebuf, gcnt, row_start, ssrc);

    const int agg_grid = (N_NODES + 3) / 4;

    // layer 1: [t|h_pre] = x @ [W1l;W1r]^T (+b1); h = relu(h_pre + mean t[nbrs])
    k_gemm_mfma<true, false><<<640, 256, 0, stream>>>(x, wc1, b1, tb, hx);
    k_agg<true, false><<<agg_grid, 256, 0, stream>>>(tb, ssrc, row_start, hx);

    // layer 2: [t|o_pre] = hx @ [W2l;W2r]^T (+b2); out = o_pre + mean t[nbrs]
    k_gemm_mfma<false, true><<<640, 256, 0, stream>>>(hx, wc2, b2, tb, out);
    k_agg<false, true><<<agg_grid, 256, 0, stream>>>(tb, ssrc, row_start, out);
}

// Round 7
// 249.404 us; speedup vs baseline: 1.3312x; 1.3312x over previous
//
#include <hip/hip_runtime.h>

#define N_NODES 100000
#define N_EDGES 1600000
#define D 128
#define NBUCK 782           // ceil(N_NODES / 128)
#define BSTRIDE 2560        // fixed slots per bucket (avg 2046, +5 sigma safe)

typedef __attribute__((ext_vector_type(8))) short short8v;
typedef __attribute__((ext_vector_type(4))) float f32x4;

__device__ __forceinline__ unsigned short f2bf(float f) {
    unsigned int u = __float_as_uint(f);
    unsigned int r = (u + 0x7fffu + ((u >> 16) & 1u)) >> 16;
    return (unsigned short)r;
}
__device__ __forceinline__ float bf2f(unsigned int lo16) {
    return __uint_as_float(lo16 << 16);
}
__device__ __forceinline__ short8v zero8() {
    short8v z = {0, 0, 0, 0, 0, 0, 0, 0};
    return z;
}

// ---------------- prep: pack weights bf16, zero bucket cursors ----------------
// wc1: [256][128]  rows 0..127 = W1l, 128..255 = W1r   (K=128 GEMM, dual output)
// wc2: [128][256]  cols 0..127 = W2l k, 128..255 = W2r k (K=256 fused GEMM)
__global__ void k_prep(const float* __restrict__ W1l, const float* __restrict__ W1r,
                       const float* __restrict__ W2l, const float* __restrict__ W2r,
                       unsigned short* __restrict__ wc1, unsigned short* __restrict__ wc2,
                       int* __restrict__ gcnt) {
    int idx = blockIdx.x * 256 + threadIdx.x;
    if (idx < 16384)       wc1[idx] = f2bf(W1l[idx]);
    else if (idx < 32768)  wc1[idx] = f2bf(W1r[idx - 16384]);
    else if (idx < 65536) {
        int j = idx - 32768;
        int o = j >> 8, k2 = j & 255;
        float v = (k2 < 128) ? W2l[o * 128 + k2] : W2r[o * 128 + (k2 - 128)];
        wc2[j] = f2bf(v);
    }
    else if (idx - 65536 < NBUCK) gcnt[idx - 65536] = 0;
}

// ---------------- scatter edges into fixed-stride buckets (by dst>>7) ----------------
__global__ __launch_bounds__(256) void k_bscatter(const int* __restrict__ src,
                                                  const int* __restrict__ dst,
                                                  int* __restrict__ gcnt,
                                                  unsigned int* __restrict__ ebuf) {
    __shared__ int cnt[NBUCK];
    __shared__ int base[NBUCK];
    const int t = threadIdx.x;
    const int e0 = blockIdx.x * 4096;
    for (int i = t; i < NBUCK; i += 256) cnt[i] = 0;
    __syncthreads();
#pragma unroll
    for (int u = 0; u < 16; ++u) {
        int e = e0 + u * 256 + t;
        if (e < N_EDGES) atomicAdd(&cnt[dst[e] >> 7], 1);
    }
    __syncthreads();
    for (int i = t; i < NBUCK; i += 256) {
        int c = cnt[i];
        base[i] = c ? atomicAdd(&gcnt[i], c) : 0;
        cnt[i] = 0;
    }
    __syncthreads();
#pragma unroll
    for (int u = 0; u < 16; ++u) {
        int e = e0 + u * 256 + t;
        if (e < N_EDGES) {
            int d = dst[e];
            int b = d >> 7;
            int pos = b * BSTRIDE + base[b] + atomicAdd(&cnt[b], 1);
            ebuf[pos] = ((unsigned int)(d & 127) << 17) | (unsigned int)src[e];
        }
    }
}

// ---------------- per-bucket counting sort by local dst ----------------
__global__ __launch_bounds__(256) void k_bsort(const unsigned int* __restrict__ ebuf,
                                               const int* __restrict__ gcnt,
                                               int* __restrict__ row_start,
                                               int* __restrict__ ssrc) {
    __shared__ int h[128];
    __shared__ int sc[128];
    const int b = blockIdx.x;
    const int t = threadIdx.x;
    const int eb = b * BSTRIDE;
    const int n = gcnt[b];
    if (t < 128) h[t] = 0;
    __syncthreads();
    for (int e = t; e < n; e += 256)
        atomicAdd(&h[ebuf[eb + e] >> 17], 1);
    __syncthreads();
    if (t < 128) sc[t] = h[t];
    __syncthreads();
    for (int o = 1; o < 128; o <<= 1) {
        int add = 0;
        if (t < 128 && t >= o) add = sc[t - o];
        __syncthreads();
        if (t < 128) sc[t] += add;
        __syncthreads();
    }
    if (t < 128) {
        int excl = sc[t] - h[t];
        row_start[b * 129 + t] = eb + excl;
        h[t] = excl;            // becomes cursor
    }
    if (t == 0) row_start[b * 129 + 128] = eb + n;
    __syncthreads();
    for (int e = t; e < n; e += 256) {
        unsigned int pk = ebuf[eb + e];
        int dl = pk >> 17;
        int pos = eb + atomicAdd(&h[dl], 1);
        ssrc[pos] = (int)(pk & 0x1ffffu);
    }
}

// ---------------- layer-1 GEMM: [N x 128]f32 @ [128 x 256] -> t1 bf16 | h_pre bf16 ----------------
__global__ __launch_bounds__(256) void k_gemm1(
    const float* __restrict__ Af,            // x f32
    const unsigned short* __restrict__ Bt,   // wc1 [256][128]
    const float* __restrict__ bias,          // b1
    unsigned short* __restrict__ Tout,       // t1 [N][128] bf16
    unsigned short* __restrict__ Hout)       // h_pre [N][128] bf16
{
    const int wid = threadIdx.x >> 6;
    const int lane = threadIdx.x & 63;
    const int l15 = lane & 15, lg = lane >> 4;
    const int col_base = wid * 64;

    short8v bfrag[4][4];
#pragma unroll
    for (int cg = 0; cg < 4; ++cg)
#pragma unroll
        for (int ks = 0; ks < 4; ++ks)
            bfrag[cg][ks] = *(const short8v*)&Bt[(size_t)(col_base + cg * 16 + l15) * 128
                                                 + ks * 32 + lg * 8];
    float bv[4];
#pragma unroll
    for (int cg = 0; cg < 4; ++cg)
        bv[cg] = (wid >= 2) ? bias[(wid - 2) * 64 + cg * 16 + l15] : 0.0f;

    const int ntiles = (N_NODES + 63) / 64;
    for (int tile = blockIdx.x; tile < ntiles; tile += gridDim.x) {
        const int row0 = tile * 64;
        f32x4 acc[4][4];
#pragma unroll
        for (int rg = 0; rg < 4; ++rg)
#pragma unroll
            for (int cg = 0; cg < 4; ++cg)
                acc[rg][cg] = (f32x4){0.f, 0.f, 0.f, 0.f};

#pragma unroll
        for (int rg = 0; rg < 4; ++rg) {
            const int arow = row0 + rg * 16 + l15;
            short8v afrag[4];
            if (arow < N_NODES) {
#pragma unroll
                for (int ks = 0; ks < 4; ++ks) {
                    float4 p0 = *(const float4*)&Af[(size_t)arow * 128 + ks * 32 + lg * 8];
                    float4 p1 = *(const float4*)&Af[(size_t)arow * 128 + ks * 32 + lg * 8 + 4];
                    short8v f;
                    f[0] = (short)f2bf(p0.x); f[1] = (short)f2bf(p0.y);
                    f[2] = (short)f2bf(p0.z); f[3] = (short)f2bf(p0.w);
                    f[4] = (short)f2bf(p1.x); f[5] = (short)f2bf(p1.y);
                    f[6] = (short)f2bf(p1.z); f[7] = (short)f2bf(p1.w);
                    afrag[ks] = f;
                }
            } else {
#pragma unroll
                for (int ks = 0; ks < 4; ++ks) afrag[ks] = zero8();
            }
#pragma unroll
            for (int cg = 0; cg < 4; ++cg)
#pragma unroll
                for (int ks = 0; ks < 4; ++ks)
                    acc[rg][cg] = __builtin_amdgcn_mfma_f32_16x16x32_bf16(
                        afrag[ks], bfrag[cg][ks], acc[rg][cg], 0, 0, 0);
        }

        unsigned short* outp = (wid < 2) ? Tout : Hout;
        const int cb = (wid < 2) ? col_base : col_base - 128;
        const bool addb = (wid >= 2);
#pragma unroll
        for (int rg = 0; rg < 4; ++rg) {
            const int rbase = row0 + rg * 16 + lg * 4;
#pragma unroll
            for (int cg = 0; cg < 4; ++cg) {
                const int col = cb + cg * 16 + l15;
#pragma unroll
                for (int i = 0; i < 4; ++i) {
                    int row = rbase + i;
                    if (row < N_NODES) {
                        float v = acc[rg][cg][i] + (addb ? bv[cg] : 0.0f);
                        outp[(size_t)row * 128 + col] = f2bf(v);
                    }
                }
            }
        }
    }
}

// ---------------- layer-2 fused GEMM: out = [m2|h] @ wc2^T + b2  (K=256, f32 out) -------
__global__ __launch_bounds__(256) void k_gemm2(
    const unsigned short* __restrict__ M,    // m2 [N][128] bf16
    const unsigned short* __restrict__ H,    // h  [N][128] bf16
    const unsigned short* __restrict__ Bt,   // wc2 [128][256]
    const float* __restrict__ bias,          // b2
    float* __restrict__ out)
{
    const int wid = threadIdx.x >> 6;        // 4 waves x 32 cols
    const int lane = threadIdx.x & 63;
    const int l15 = lane & 15, lg = lane >> 4;
    const int col_base = wid * 32;

    short8v bfrag[2][8];
#pragma unroll
    for (int cg = 0; cg < 2; ++cg)
#pragma unroll
        for (int ks = 0; ks < 8; ++ks)
            bfrag[cg][ks] = *(const short8v*)&Bt[(size_t)(col_base + cg * 16 + l15) * 256
                                                 + ks * 32 + lg * 8];
    float bv[2];
#pragma unroll
    for (int cg = 0; cg < 2; ++cg)
        bv[cg] = bias[col_base + cg * 16 + l15];

    const int ntiles = (N_NODES + 63) / 64;
    for (int tile = blockIdx.x; tile < ntiles; tile += gridDim.x) {
        const int row0 = tile * 64;
        f32x4 acc[4][2];
#pragma unroll
        for (int rg = 0; rg < 4; ++rg)
#pragma unroll
            for (int cg = 0; cg < 2; ++cg)
                acc[rg][cg] = (f32x4){0.f, 0.f, 0.f, 0.f};

#pragma unroll
        for (int rg = 0; rg < 4; ++rg) {
            const int arow = row0 + rg * 16 + l15;
            short8v afrag[8];
            if (arow < N_NODES) {
#pragma unroll
                for (int ks = 0; ks < 4; ++ks) {
                    afrag[ks]     = *(const short8v*)&M[(size_t)arow * 128 + ks * 32 + lg * 8];
                    afrag[ks + 4] = *(const short8v*)&H[(size_t)arow * 128 + ks * 32 + lg * 8];
                }
            } else {
#pragma unroll
                for (int ks = 0; ks < 8; ++ks) afrag[ks] = zero8();
            }
#pragma unroll
            for (int cg = 0; cg < 2; ++cg)
#pragma unroll
                for (int ks = 0; ks < 8; ++ks)
                    acc[rg][cg] = __builtin_amdgcn_mfma_f32_16x16x32_bf16(
                        afrag[ks], bfrag[cg][ks], acc[rg][cg], 0, 0, 0);
        }

#pragma unroll
        for (int rg = 0; rg < 4; ++rg) {
            const int rbase = row0 + rg * 16 + lg * 4;
#pragma unroll
            for (int cg = 0; cg < 2; ++cg) {
                const int col = col_base + cg * 16 + l15;
#pragma unroll
                for (int i = 0; i < 4; ++i) {
                    int row = rbase + i;
                    if (row < N_NODES)
                        out[(size_t)row * 128 + col] = acc[rg][cg][i] + bv[cg];
                }
            }
        }
    }
}

// ---------------- pull aggregation: wave per node, register acc, 8-deep MLP ----------------
// RMW=true : io = relu(io + inv*sum)   (layer 1, in-place on h_pre)
// RMW=false: io = inv*sum              (layer 2, pure write of mean(h))
template <bool RMW>
__global__ __launch_bounds__(256) void k_agg(
    const unsigned short* __restrict__ t_mat,   // gather source [N][128] bf16
    const int* __restrict__ ssrc,               // srcs sorted by dst (bucket-local CSR)
    const int* __restrict__ row_start,          // 129 per bucket
    unsigned short* __restrict__ io)            // [N][128] bf16
{
    int w = (blockIdx.x * blockDim.x + threadIdx.x) >> 6;
    int lane = threadIdx.x & 63;
    if (w >= N_NODES) return;
    const int b = w >> 7, dl = w & 127;
    const int rs = row_start[b * 129 + dl];
    const int re = row_start[b * 129 + dl + 1];
    const int d = re - rs;

    float cx = 0.f, cy = 0.f;
    if (RMW) {
        unsigned int cur = *((const unsigned int*)io + (size_t)w * 64 + lane);
        cx = bf2f(cur & 0xffffu);
        cy = __uint_as_float(cur & 0xffff0000u);
    }

    const unsigned int* tlane = (const unsigned int*)t_mat + lane;   // +j*64 per row
    float ax = 0.f, ay = 0.f;
    for (int q0 = rs; q0 < re; q0 += 64) {
        int nb = 0;
        if (q0 + lane < re) nb = ssrc[q0 + lane];
        const int m = min(64, re - q0);
        int q = 0;
        for (; q + 8 <= m; q += 8) {
            unsigned int v0 = tlane[(size_t)__shfl(nb, q) * 64];
            unsigned int v1 = tlane[(size_t)__shfl(nb, q + 1) * 64];
            unsigned int v2 = tlane[(size_t)__shfl(nb, q + 2) * 64];
            unsigned int v3 = tlane[(size_t)__shfl(nb, q + 3) * 64];
            unsigned int v4 = tlane[(size_t)__shfl(nb, q + 4) * 64];
            unsigned int v5 = tlane[(size_t)__shfl(nb, q + 5) * 64];
            unsigned int v6 = tlane[(size_t)__shfl(nb, q + 6) * 64];
            unsigned int v7 = tlane[(size_t)__shfl(nb, q + 7) * 64];
            ax += bf2f(v0 & 0xffffu) + bf2f(v1 & 0xffffu)
                + bf2f(v2 & 0xffffu) + bf2f(v3 & 0xffffu)
                + bf2f(v4 & 0xffffu) + bf2f(v5 & 0xffffu)
                + bf2f(v6 & 0xffffu) + bf2f(v7 & 0xffffu);
            ay += __uint_as_float(v0 & 0xffff0000u) + __uint_as_float(v1 & 0xffff0000u)
                + __uint_as_float(v2 & 0xffff0000u) + __uint_as_float(v3 & 0xffff0000u)
                + __uint_as_float(v4 & 0xffff0000u) + __uint_as_float(v5 & 0xffff0000u)
                + __uint_as_float(v6 & 0xffff0000u) + __uint_as_float(v7 & 0xffff0000u);
        }
        for (; q < m; ++q) {
            unsigned int v = tlane[(size_t)__shfl(nb, q) * 64];
            ax += bf2f(v & 0xffffu);
            ay += __uint_as_float(v & 0xffff0000u);
        }
    }
    const float inv = 1.0f / (float)max(d, 1);
    float rx, ry;
    if (RMW) {
        rx = fmaxf(cx + inv * ax, 0.f);
        ry = fmaxf(cy + inv * ay, 0.f);
    } else {
        rx = inv * ax;
        ry = inv * ay;
    }
    *((unsigned int*)io + (size_t)w * 64 + lane) =
        (unsigned int)f2bf(rx) | ((unsigned int)f2bf(ry) << 16);
}

// ---------------- launch ----------------

extern "C" void kernel_launch(void* const* d_in, const int* in_sizes, int n_in,
                              void* d_out, int out_size, void* d_ws, size_t ws_size,
                              hipStream_t stream) {
    const float* x   = (const float*)d_in[0];
    const int*   ei  = (const int*)d_in[1];
    const float* W1l = (const float*)d_in[2];
    const float* W1r = (const float*)d_in[3];
    const float* b1  = (const float*)d_in[4];
    const float* W2l = (const float*)d_in[5];
    const float* W2r = (const float*)d_in[6];
    const float* b2  = (const float*)d_in[7];
    float* out = (float*)d_out;

    const int* src = ei;
    const int* dst = ei + N_EDGES;

    char* p = (char*)d_ws;
    auto alloc = [&](size_t bytes) {
        char* r = p;
        p += (bytes + 255) & ~(size_t)255;
        return r;
    };
    unsigned short* tb = (unsigned short*)alloc((size_t)N_NODES * D * 2);   // t1 / m2
    unsigned short* hx = (unsigned short*)alloc((size_t)N_NODES * D * 2);   // h
    unsigned int*   ebuf = (unsigned int*)alloc((size_t)NBUCK * BSTRIDE * 4); // 8MB
    int*   ssrc      = (int*)alloc((size_t)NBUCK * BSTRIDE * 4);              // 8MB
    int*   gcnt      = (int*)alloc(NBUCK * sizeof(int));
    int*   row_start = (int*)alloc((size_t)NBUCK * 129 * sizeof(int));
    unsigned short* wc1 = (unsigned short*)alloc(256 * 128 * 2);
    unsigned short* wc2 = (unsigned short*)alloc(128 * 256 * 2);

    // prep (weights + cursor zero) -> scatter -> per-bucket sort
    k_prep<<<(65536 + NBUCK + 255) / 256, 256, 0, stream>>>(W1l, W1r, W2l, W2r, wc1, wc2, gcnt);
    k_bscatter<<<(N_EDGES + 4095) / 4096, 256, 0, stream>>>(src, dst, gcnt, ebuf);
    k_bsort<<<NBUCK, 256, 0, stream>>>(ebuf, gcnt, row_start, ssrc);

    const int agg_grid = (N_NODES + 3) / 4;

    // layer 1: [t1|h_pre] = x @ [W1l;W1r]^T (+b1); h = relu(h_pre + mean t1[nbrs])
    k_gemm1<<<640, 256, 0, stream>>>(x, wc1, b1, tb, hx);
    k_agg<true><<<agg_grid, 256, 0, stream>>>(tb, ssrc, row_start, hx);

    // layer 2: m2 = mean h[nbrs]; out = [m2|h] @ [W2l|W2r]^T + b2
    k_agg<false><<<agg_grid, 256, 0, stream>>>(hx, ssrc, row_start, tb);
    k_gemm2<<<640, 256, 0, stream>>>(tb, hx, wc2, b2, out);
}